// Round 7
// baseline (761.375 us; speedup 1.0000x reference)
//
#include <hip/hip_runtime.h>

// ChebyshevKAN on MI355X (gfx950).
// Reformulation: einsum(bid,oid->bo) + x@base_w.T  ==  Xaug @ W^T with
//   Xaug[b, i*6+d] = T_{d+1}(tanh(x_i))  (d=0..4),  Xaug[b, i*6+5] = x_i
//   W[o,    i*6+d] = coeff[o,i,d+1]      (d=0..4),  W[o,    i*6+5] = base_w[o,i]
// T0==1 slice folds into bias:  bias'[o] = bias[o] + sum_i coeff[o,i,0].
//
// R12 == R11 resubmit (R11 bench died in harness async layer; full ledger
// re-audit found no kernel-side hang/fault -- see session journal).
// R11: R0/R6/R7/R9/R10 all pinned at 30-35% MfmaUtil despite orthogonal
// schedule fixes -> the shared trait is 1 block/CU: every barrier stalls the
// whole CU (LDS ~1150cyc vs MFMA ~1031cyc per body + skew = dead time).
// R0's 4-block/CU gemm2 kernel is the lineage's only overlap winner (m114:
// inter-wave/block overlap fills stalls). So: gemm1 = 256x128 tile, 4 waves,
// ring-3 BK=32 (72 KiB LDS) -> 2 INDEPENDENT blocks/CU; barriers sync only
// 4 waves; co-resident block fills stalls. Counted-vmcnt ledger (R10-proven):
// steady vmcnt(6) drains exactly stage(t+1) (2 stages x 6 loads in flight);
// body t: [vmcnt(6) lgkm(0); barrier] RD(t+1 <- slot (t+1)%3);
//         STAGE(t+3 -> slot t%3); MFMA(t).   Unroll x6 (2 banks x 3 slots).
// WAR: slot t%3 last read body t-1; lgkm(0)+barrier at body t covers it.
// gemm2 = R0-verified 64x128 kernel (4 blocks/CU, ~490 TF measured).

typedef __bf16 bf16x8 __attribute__((ext_vector_type(8)));
typedef float f32x4 __attribute__((ext_vector_type(4)));
typedef unsigned short u16x8 __attribute__((ext_vector_type(8)));

__device__ __forceinline__ unsigned short f2bf(float f) {
    unsigned int u = __float_as_uint(f);
    unsigned int r = (u + 0x7FFFu + ((u >> 16) & 1u)) >> 16;
    return (unsigned short)r;
}
__device__ __forceinline__ float bf2f(unsigned short b) {
    return __uint_as_float(((unsigned int)b) << 16);
}

__device__ __forceinline__ float fast_tanh(float x) {
    float a = fminf(fmaxf(x, -15.f), 15.f);
    float e = __expf(2.f * a);
    return 1.f - 2.f * __builtin_amdgcn_rcpf(e + 1.f);
}
__device__ __forceinline__ float fast_silu(float y) {
    float a = fminf(fmaxf(y, -30.f), 30.f);
    return y * __builtin_amdgcn_rcpf(1.f + __expf(-a));
}

__device__ __forceinline__ void cheb_pack(float s, unsigned short* o6) {
    float u  = fast_tanh(s);
    float T1 = u;
    float T2 = 2.f * u * u - 1.f;
    float T3 = 2.f * u * T2 - T1;
    float T4 = 2.f * u * T3 - T2;
    float T5 = 2.f * u * T4 - T3;
    o6[0] = f2bf(T1); o6[1] = f2bf(T2); o6[2] = f2bf(T3);
    o6[3] = f2bf(T4); o6[4] = f2bf(T5); o6[5] = f2bf(s);
}

__device__ __forceinline__ void load_lds16(const void* g, void* l) {
    __builtin_amdgcn_global_load_lds(
        (const __attribute__((address_space(1))) void*)g,
        (__attribute__((address_space(3))) void*)l, 16, 0, 0);
}

// ---------------- prep: weights [O,I,6]+[O,I] -> W[N=O, K=I*6] bf16 ----------
__global__ __launch_bounds__(256) void prep_w_kernel(
    const float* __restrict__ coeff, const float* __restrict__ base_w,
    unsigned short* __restrict__ W, int OI)
{
    int idx = blockIdx.x * 256 + threadIdx.x;
    if (idx >= OI) return;
    const float* c = coeff + (size_t)idx * 6;
    unsigned short w0 = f2bf(c[1]), w1 = f2bf(c[2]), w2 = f2bf(c[3]),
                   w3 = f2bf(c[4]), w4 = f2bf(c[5]), w5 = f2bf(base_w[idx]);
    unsigned int* d = (unsigned int*)(W + (size_t)idx * 6);
    d[0] = w0 | ((unsigned int)w1 << 16);
    d[1] = w2 | ((unsigned int)w3 << 16);
    d[2] = w4 | ((unsigned int)w5 << 16);
}

__global__ __launch_bounds__(256) void prep_bias_kernel(
    const float* __restrict__ coeff, const float* __restrict__ bias,
    float* __restrict__ bp, int I)
{
    int o = blockIdx.x, tid = threadIdx.x;
    float s = 0.f;
    for (int i = tid; i < I; i += 256) s += coeff[((size_t)o * I + i) * 6];
    #pragma unroll
    for (int off = 32; off > 0; off >>= 1) s += __shfl_down(s, off);
    __shared__ float red[4];
    int lane = tid & 63, wv = tid >> 6;
    if (lane == 0) red[wv] = s;
    __syncthreads();
    if (tid == 0) bp[o] = bias[o] + red[0] + red[1] + red[2] + red[3];
}

// ---------------- expand1: x[b,1024] -> Xaug[b,6144] bf16  (block per row) ---
__global__ __launch_bounds__(256) void expand1_kernel(
    const float* __restrict__ x, unsigned short* __restrict__ Xa)
{
    int b = blockIdx.x, tid = threadIdx.x;
    f32x4 xv = *(const f32x4*)(x + (size_t)b * 1024 + tid * 4);
    alignas(16) unsigned short ov[24];
    #pragma unroll
    for (int e = 0; e < 4; e++) cheb_pack(fast_tanh(xv[e]), ov + e * 6);
    u16x8* dst = (u16x8*)(Xa + (size_t)b * 6144 + tid * 24);
    const u16x8* src = (const u16x8*)ov;
    dst[0] = src[0]; dst[1] = src[1]; dst[2] = src[2];
}

// ------------- LN + SiLU + expand2 fused (block per row of 1024, h in bf16) --
__global__ __launch_bounds__(256) void ln_silu_expand_kernel(
    const unsigned short* __restrict__ H, const float* __restrict__ gamma,
    const float* __restrict__ beta, unsigned short* __restrict__ Xa)
{
    int b = blockIdx.x, tid = threadIdx.x;
    ushort4 hb = *(const ushort4*)(H + (size_t)b * 1024 + tid * 4);
    float hv[4] = { bf2f(hb.x), bf2f(hb.y), bf2f(hb.z), bf2f(hb.w) };
    float s1 = hv[0] + hv[1] + hv[2] + hv[3];
    float s2 = hv[0]*hv[0] + hv[1]*hv[1] + hv[2]*hv[2] + hv[3]*hv[3];
    #pragma unroll
    for (int off = 32; off > 0; off >>= 1) {
        s1 += __shfl_down(s1, off);
        s2 += __shfl_down(s2, off);
    }
    __shared__ float red[8];
    __shared__ float stats[2];
    int lane = tid & 63, wv = tid >> 6;
    if (lane == 0) { red[wv] = s1; red[4 + wv] = s2; }
    __syncthreads();
    if (tid == 0) {
        float t1 = red[0] + red[1] + red[2] + red[3];
        float t2 = red[4] + red[5] + red[6] + red[7];
        float mu = t1 * (1.f / 1024.f);
        float var = t2 * (1.f / 1024.f) - mu * mu;
        stats[0] = mu;
        stats[1] = rsqrtf(var + 1e-5f);
    }
    __syncthreads();
    float mu = stats[0], rs = stats[1];
    f32x4 g  = *(const f32x4*)(gamma + tid * 4);
    f32x4 bt = *(const f32x4*)(beta  + tid * 4);
    alignas(16) unsigned short ov[24];
    #pragma unroll
    for (int e = 0; e < 4; e++) {
        float y = (hv[e] - mu) * rs * g[e] + bt[e];
        cheb_pack(fast_silu(y), ov + e * 6);
    }
    u16x8* dst = (u16x8*)(Xa + (size_t)b * 6144 + tid * 24);
    const u16x8* src = (const u16x8*)ov;
    dst[0] = src[0]; dst[1] = src[1]; dst[2] = src[2];
}

// == gemm1: 256x128 tile, 4 waves, ring-3 BK=32, 2 blocks/CU (bf16 out) ======
__global__ __launch_bounds__(256, 2) void gemm5_kernel(
    const unsigned short* __restrict__ A,   // [M,K] bf16 bits
    const unsigned short* __restrict__ Wt,  // [N,K] bf16 bits
    const float* __restrict__ bias,         // [N]
    unsigned short* __restrict__ Cout,      // [M,N] bf16
    int N, int K, int NMT)
{
    constexpr int ASZ = 256 * 32;       // shorts per A ring slot (16 KB)
    constexpr int BSZ = 128 * 32;       // shorts per B ring slot (8 KB)
    __shared__ __align__(16) unsigned short As[3 * ASZ];
    __shared__ __align__(16) unsigned short Bs[3 * BSZ];

    const int tid  = threadIdx.x;
    const int lane = tid & 63;
    const int wave = tid >> 6;          // 0..3
    const int wm   = wave >> 1;         // 0..1
    const int wn   = wave & 1;          // 0..1

    // bijective XCD swizzle (grid 512 % 8 == 0); consecutive swz-wg on one
    // XCD share nt (one 128-col W-panel = 1.5 MB, L2-resident per XCD).
    int wg = blockIdx.x;
    {
        const int nwg = gridDim.x;
        if ((nwg & 7) == 0) { const int cpx = nwg >> 3; wg = (wg & 7) * cpx + (wg >> 3); }
    }
    const int mt = wg % NMT;
    const int nt = wg / NMT;
    const size_t m0 = (size_t)mt * 256;
    const size_t n0 = (size_t)nt * 128;

    // staging: 16-row units; thread = (row = u*16 + lane/4, chunk = lane%4),
    // pre-swizzled src chunk = (lane&3) ^ ((row>>1)&3) = (lane&3)^((lane>>3)&3)
    const int cs   = (((lane & 3) ^ ((lane >> 3) & 3)) << 3);  // shorts
    const int srow = lane >> 2;
    const unsigned short* AgJ[4];
    unsigned short* AD[4];
    #pragma unroll
    for (int j = 0; j < 4; ++j) {
        const int u = wave * 4 + j;                      // 16 units
        AgJ[j] = A + (m0 + (size_t)(u * 16 + srow)) * K + cs;
        AD[j]  = As + u * 512 + lane * 8;
    }
    const unsigned short* BgJ[2];
    unsigned short* BD[2];
    #pragma unroll
    for (int j = 0; j < 2; ++j) {
        const int u = wave * 2 + j;                      // 8 units
        BgJ[j] = Wt + (n0 + (size_t)(u * 16 + srow)) * K + cs;
        BD[j]  = Bs + u * 512 + lane * 8;
    }

    // frag-read bases (XOR de-swizzle on read; key = (row>>1)&3)
    const int fr = lane & 15;
    const int cg = lane >> 4;
    const int ck = ((cg ^ ((fr >> 1) & 3)) << 3);        // shorts
    const unsigned short* PA = As + (wm * 128 + fr) * 32 + ck;
    const unsigned short* PB = Bs + (wn * 64 + fr) * 32 + ck;

    const int NT = K >> 5;              // 192 (divisible by 6)

    f32x4 acc[2][4][4];
    #pragma unroll
    for (int mh = 0; mh < 2; ++mh)
        #pragma unroll
        for (int mf = 0; mf < 4; ++mf)
            #pragma unroll
            for (int nf = 0; nf < 4; ++nf)
                acc[mh][mf][nf] = f32x4{0.f, 0.f, 0.f, 0.f};

    bf16x8 aF[8], aG[8], bF[4], bG[4];

#define STAGE(T, R_) do { \
    const size_t ko_ = (size_t)(T) * 32; \
    load_lds16(AgJ[0] + ko_, AD[0] + (R_) * ASZ); \
    load_lds16(AgJ[1] + ko_, AD[1] + (R_) * ASZ); \
    load_lds16(AgJ[2] + ko_, AD[2] + (R_) * ASZ); \
    load_lds16(AgJ[3] + ko_, AD[3] + (R_) * ASZ); \
    load_lds16(BgJ[0] + ko_, BD[0] + (R_) * BSZ); \
    load_lds16(BgJ[1] + ko_, BD[1] + (R_) * BSZ); \
} while (0)

#define RD(AF_, BF_, R_) do { \
    _Pragma("unroll") \
    for (int mh = 0; mh < 2; ++mh) \
        _Pragma("unroll") \
        for (int mf = 0; mf < 4; ++mf) \
            AF_[mh * 4 + mf] = *(const bf16x8*)(PA + (R_) * ASZ + (mh * 64 + mf * 16) * 32); \
    _Pragma("unroll") \
    for (int nf = 0; nf < 4; ++nf) \
        BF_[nf] = *(const bf16x8*)(PB + (R_) * BSZ + nf * 16 * 32); \
} while (0)

#define MM(AF_, BF_) do { \
    __builtin_amdgcn_s_setprio(1); \
    _Pragma("unroll") \
    for (int mh = 0; mh < 2; ++mh) \
        _Pragma("unroll") \
        for (int mf = 0; mf < 4; ++mf) \
            _Pragma("unroll") \
            for (int nf = 0; nf < 4; ++nf) \
                acc[mh][mf][nf] = __builtin_amdgcn_mfma_f32_16x16x32_bf16( \
                    AF_[mh * 4 + mf], BF_[nf], acc[mh][mf][nf], 0, 0, 0); \
    __builtin_amdgcn_s_setprio(0); \
} while (0)

// steady: drain exactly stage(t+1), leave 1 stage (6 loads) in flight
#define W6() do { \
    asm volatile("s_waitcnt vmcnt(6) lgkmcnt(0)" ::: "memory"); \
    __builtin_amdgcn_s_barrier(); } while (0)
#define W0() do { \
    asm volatile("s_waitcnt vmcnt(0) lgkmcnt(0)" ::: "memory"); \
    __builtin_amdgcn_s_barrier(); } while (0)

    // prologue: stage T0,T1,T2 -> slots 0,1,2; drain T0; read frags(T0)
    STAGE(0, 0); STAGE(1, 1); STAGE(2, 2);
    asm volatile("s_waitcnt vmcnt(12)" ::: "memory");
    __builtin_amdgcn_s_barrier();
    RD(aF, bF, 0);

    // main: unroll x6 = LCM(2 frag banks, 3 ring slots); body t stages t+3
    for (int t = 0; t < NT - 8; t += 6) {
        W6(); RD(aG, bG, 1); STAGE(t + 3, 0); MM(aF, bF);   // body t+0
        W6(); RD(aF, bF, 2); STAGE(t + 4, 1); MM(aG, bG);   // body t+1
        W6(); RD(aG, bG, 0); STAGE(t + 5, 2); MM(aF, bF);   // body t+2
        W6(); RD(aF, bF, 1); STAGE(t + 6, 0); MM(aG, bG);   // body t+3
        W6(); RD(aG, bG, 2); STAGE(t + 7, 1); MM(aF, bF);   // body t+4
        W6(); RD(aF, bF, 0); STAGE(t + 8, 2); MM(aG, bG);   // body t+5
    }
    // tail: bodies NT-6 .. NT-1  (NT-6 is even multiple of 6 -> bank aF first)
    W6(); RD(aG, bG, 1); STAGE(NT - 3, 0); MM(aF, bF);      // body NT-6
    W6(); RD(aF, bF, 2); STAGE(NT - 2, 1); MM(aG, bG);      // body NT-5
    W6(); RD(aG, bG, 0); STAGE(NT - 1, 2); MM(aF, bF);      // body NT-4
    W6(); RD(aF, bF, 1); MM(aG, bG);                        // body NT-3
    W0(); RD(aG, bG, 2); MM(aF, bF);                        // body NT-2
    asm volatile("s_waitcnt lgkmcnt(0)" ::: "memory");
    MM(aG, bG);                                             // body NT-1

#undef STAGE
#undef RD
#undef MM
#undef W6
#undef W0

    // C/D layout (verified): col = lane&15, row = (lane>>4)*4 + reg
    const size_t rbase0 = m0 + wm * 128 + ((lane >> 4) << 2);
    const int cb = lane & 15;
    int colg[4]; float bv[4];
    #pragma unroll
    for (int nf = 0; nf < 4; ++nf) {
        colg[nf] = (int)n0 + wn * 64 + nf * 16 + cb;
        bv[nf] = bias[colg[nf]];
    }
    #pragma unroll
    for (int mh = 0; mh < 2; ++mh)
        #pragma unroll
        for (int mf = 0; mf < 4; ++mf) {
            const size_t rg0 = rbase0 + mh * 64 + mf * 16;
            #pragma unroll
            for (int r = 0; r < 4; ++r) {
                const size_t rowoff = (rg0 + r) * (size_t)N;
                #pragma unroll
                for (int nf = 0; nf < 4; ++nf)
                    Cout[rowoff + colg[nf]] = f2bf(acc[mh][mf][nf][r] + bv[nf]);
            }
        }
}

// ============ gemm2: R0-verified m97-style BM=64 x 128 tile (f32 out) ========
__global__ __launch_bounds__(256, 4) void gemm_kernel(
    const unsigned short* __restrict__ A,   // [M,K] bf16 bits
    const unsigned short* __restrict__ Wt,  // [N,K] bf16 bits
    const float* __restrict__ bias,         // [N]
    float* __restrict__ Cout,               // [M,N] f32
    int N, int K)
{
    constexpr int BM = 64;
    constexpr int MI = BM / 32;
    __shared__ __align__(16) unsigned short As[BM * 64];
    __shared__ __align__(16) unsigned short Bs[128 * 64];
    const int tid  = threadIdx.x;
    const int lane = tid & 63;
    const int wave = tid >> 6;
    const int ntn  = N >> 7;

    int bkid = blockIdx.x;
    const int nm = gridDim.x / ntn;
    int mt, nt;
    if ((nm & 7) == 0) {
        const int mg = nm >> 3;
        const int s  = bkid >> 3;
        const int q  = s / ntn;
        mt = (bkid & 7) * mg + q;
        nt = s - q * ntn;
    } else {
        mt = bkid / ntn; nt = bkid % ntn;
    }
    const size_t m0 = (size_t)mt * BM;
    const size_t n0 = (size_t)nt << 7;

    const int wr = (wave >> 1) * (BM / 2);
    const int wc = (wave & 1) * 64;
    const int fr = lane & 15;
    const int cg = lane >> 4;
    const int srow = tid >> 3;
    const int schunk = (tid & 7) ^ (srow & 7);

    const int fr7 = fr & 7;
    const unsigned short* fA0 = As + (wr + fr) * 64 + ((cg    ) ^ fr7) * 8;
    const unsigned short* fA1 = As + (wr + fr) * 64 + ((cg + 4) ^ fr7) * 8;
    const unsigned short* fB0 = Bs + (wc + fr) * 64 + ((cg    ) ^ fr7) * 8;
    const unsigned short* fB1 = Bs + (wc + fr) * 64 + ((cg + 4) ^ fr7) * 8;

    const unsigned short* Agu = A  + m0 * (size_t)K;
    const unsigned short* Bgu = Wt + n0 * (size_t)K;
    const int loff = srow * K + schunk * 8;

    f32x4 acc[MI][4];
    #pragma unroll
    for (int i = 0; i < MI; i++)
        #pragma unroll
        for (int j = 0; j < 4; j++) acc[i][j] = f32x4{0.f, 0.f, 0.f, 0.f};

    for (int k0 = 0; k0 < K; k0 += 64) {
        const unsigned short* ak = Agu + k0;
        const unsigned short* bk = Bgu + k0;
        #pragma unroll
        for (int s = 0; s < BM / 32; ++s)
            load_lds16(ak + s * 32 * K + loff, &As[(s * 256 + wave * 64) * 8]);
        #pragma unroll
        for (int s = 0; s < 4; ++s)
            load_lds16(bk + s * 32 * K + loff, &Bs[(s * 256 + wave * 64) * 8]);
        __syncthreads();

        bf16x8 af[MI], bfr[4];
        #pragma unroll
        for (int i = 0; i < MI; i++) af[i]  = *(const bf16x8*)(fA0 + i * 1024);
        #pragma unroll
        for (int j = 0; j < 4; j++)  bfr[j] = *(const bf16x8*)(fB0 + j * 1024);
        #pragma unroll
        for (int i = 0; i < MI; i++)
            #pragma unroll
            for (int j = 0; j < 4; j++)
                acc[i][j] = __builtin_amdgcn_mfma_f32_16x16x32_bf16(
                    af[i], bfr[j], acc[i][j], 0, 0, 0);
        #pragma unroll
        for (int i = 0; i < MI; i++) af[i]  = *(const bf16x8*)(fA1 + i * 1024);
        #pragma unroll
        for (int j = 0; j < 4; j++)  bfr[j] = *(const bf16x8*)(fB1 + j * 1024);
        #pragma unroll
        for (int i = 0; i < MI; i++)
            #pragma unroll
            for (int j = 0; j < 4; j++)
                acc[i][j] = __builtin_amdgcn_mfma_f32_16x16x32_bf16(
                    af[i], bfr[j], acc[i][j], 0, 0, 0);
        __syncthreads();
    }

    const int rbase = wr + (lane >> 4) * 4;
    const int cbase = wc + (lane & 15);
    #pragma unroll
    for (int j = 0; j < 4; j++) {
        const int col = (int)n0 + cbase + j * 16;
        const float bv = bias[col];
        #pragma unroll
        for (int i = 0; i < MI; i++) {
            #pragma unroll
            for (int r = 0; r < 4; r++) {
                const size_t idx = (m0 + rbase + i * 16 + r) * N + col;
                Cout[idx] = acc[i][j][r] + bv;
            }
        }
    }
}

extern "C" void kernel_launch(void* const* d_in, const int* in_sizes, int n_in,
                              void* d_out, int out_size, void* d_ws, size_t ws_size,
                              hipStream_t stream)
{
    const float* x       = (const float*)d_in[0];
    const float* coeff1  = (const float*)d_in[1];
    const float* base_w1 = (const float*)d_in[2];
    const float* bias1   = (const float*)d_in[3];
    const float* gamma   = (const float*)d_in[4];
    const float* beta    = (const float*)d_in[5];
    const float* coeff2  = (const float*)d_in[6];
    const float* base_w2 = (const float*)d_in[7];
    const float* bias2   = (const float*)d_in[8];
    float* out = (float*)d_out;

    const int B = 16384, D0 = 1024, D1 = 1024, D2 = 512;
    const int K1 = D0 * 6, K2 = D1 * 6;   // 6144 each

    char* base = (char*)d_ws;
    size_t off = 0;
    unsigned short* W1 = (unsigned short*)(base + off); off += (size_t)D1 * K1 * 2;
    unsigned short* W2 = (unsigned short*)(base + off); off += (size_t)D2 * K2 * 2;
    float* b1p = (float*)(base + off); off += (size_t)D1 * 4;
    float* b2p = (float*)(base + off); off += (size_t)D2 * 4;
    off = (off + 255) & ~(size_t)255;

    size_t per_row = (size_t)K1 * 2 + (size_t)D1 * 2;   // 14336 B
    long long avail = (long long)ws_size - (long long)off;
    long long mcl = avail > 0 ? avail / (long long)per_row : 0;
    int Mc = (int)((mcl / 256) * 256);
    if (Mc < 256) Mc = 256;
    if (Mc > B) Mc = B;

    unsigned short* Xa = (unsigned short*)(base + off);
    unsigned short* h = (unsigned short*)(base + off + (size_t)Mc * K1 * 2);

    prep_w_kernel<<<(D1 * D0 + 255) / 256, 256, 0, stream>>>(coeff1, base_w1, W1, D1 * D0);
    prep_w_kernel<<<(D2 * D1 + 255) / 256, 256, 0, stream>>>(coeff2, base_w2, W2, D2 * D1);
    prep_bias_kernel<<<D1, 256, 0, stream>>>(coeff1, bias1, b1p, D0);
    prep_bias_kernel<<<D2, 256, 0, stream>>>(coeff2, bias2, b2p, D1);

    for (int m0 = 0; m0 < B; m0 += Mc) {
        int rows = (B - m0 < Mc) ? (B - m0) : Mc;
        int nmt = rows / 256;
        expand1_kernel<<<rows, 256, 0, stream>>>(x + (size_t)m0 * D0, Xa);
        gemm5_kernel<<<nmt * (D1 / 128), 256, 0, stream>>>(
            Xa, W1, b1p, h, D1, K1, nmt);
        ln_silu_expand_kernel<<<rows, 256, 0, stream>>>(h, gamma, beta, Xa);
        gemm_kernel<<<(rows / 64) * (D2 / 128), 256, 0, stream>>>(
            Xa, W2, b2p, out + (size_t)m0 * D2, D2, K2);
    }
}